// Round 1
// baseline (413.216 us; speedup 1.0000x reference)
//
#include <hip/hip_runtime.h>

#define D 128

// ---------------- setup kernels ----------------

__global__ __launch_bounds__(256) void k_init(int* cnt, int N, float* accB, int* cntB, int B) {
  int i = blockIdx.x * 256 + threadIdx.x;
  if (i < N) cnt[i] = 1;                 // self-loop
  if (i < B) { accB[i] = 0.f; cntB[i] = 0; }
}

__global__ __launch_bounds__(256) void k_count(const int* __restrict__ ei, int E,
                                               const int* __restrict__ batch, int N,
                                               int* cnt, int* cntB) {
  int i = blockIdx.x * 256 + threadIdx.x;
  if (i < E) {
    atomicAdd(&cnt[ei[E + i]], 1);       // dst = row 1 of edge_index
  } else if (i < E + N) {
    atomicAdd(&cntB[batch[i - E]], 1);   // nodes per graph
  }
}

__global__ __launch_bounds__(256) void k_dinv(const int* __restrict__ cnt, float* dinv, int N) {
  int i = blockIdx.x * 256 + threadIdx.x;
  if (i < N) dinv[i] = rsqrtf((float)cnt[i]);   // deg >= 1 always
}

// exclusive scan of cnt[0..N) -> offs, cursor; offs[N] = total. Single block.
__global__ __launch_bounds__(1024) void k_scan(const int* __restrict__ cnt,
                                               int* offs, int* cursor, int N) {
  __shared__ int buf[1024];
  __shared__ int carry_s;
  int tid = threadIdx.x;
  if (tid == 0) carry_s = 0;
  __syncthreads();
  for (int base = 0; base < N; base += 1024) {
    int i = base + tid;
    int v = (i < N) ? cnt[i] : 0;
    buf[tid] = v;
    __syncthreads();
    for (int s = 1; s < 1024; s <<= 1) {
      int t = (tid >= s) ? buf[tid - s] : 0;
      __syncthreads();
      buf[tid] += t;
      __syncthreads();
    }
    int carry = carry_s;
    if (i < N) { int e = carry + buf[tid] - v; offs[i] = e; cursor[i] = e; }
    __syncthreads();
    if (tid == 0) carry_s = carry + buf[1023];
    __syncthreads();
  }
  if (tid == 0) offs[N] = carry_s;
}

__global__ __launch_bounds__(256) void k_fill(const int* __restrict__ ei, int E, int N,
                                              const float* __restrict__ dinv,
                                              int* cursor, int* csr_src, float* normv) {
  int i = blockIdx.x * 256 + threadIdx.x;
  if (i < E) {
    int s = ei[i];        // src
    int d = ei[E + i];    // dst
    int p = atomicAdd(&cursor[d], 1);
    csr_src[p] = s;
    normv[p] = dinv[s] * dinv[d];
  } else if (i < E + N) {
    int n_ = i - E;       // self-loop
    int p = atomicAdd(&cursor[n_], 1);
    csr_src[p] = n_;
    float dn = dinv[n_];
    normv[p] = dn * dn;
  }
}

// ---------------- GEMM: C[N x 128] = A[N x 128] @ W[128 x 128] ----------------
// block = 256 threads computes 32 rows x 128 cols; K tiled by 32.
__global__ __launch_bounds__(256) void k_gemm(const float* __restrict__ A,
                                              const float* __restrict__ W,
                                              float* __restrict__ C, int N) {
  __shared__ float As[32][36];    // transposed A tile, padded
  __shared__ float Ws[32][128];
  int tid = threadIdx.x;
  int tx = tid & 31;              // col group: cols tx*4 .. tx*4+3
  int ty = tid >> 5;              // row group: rows ty*4 .. ty*4+3 (0..7)
  int r0 = blockIdx.x * 32;
  float acc[4][4] = {};

  for (int k0 = 0; k0 < 128; k0 += 32) {
    // stage W tile: 32 rows x 128 cols = 1024 float4
    for (int i = tid; i < 1024; i += 256) {
      int kk = i >> 5, j4 = i & 31;
      float4 w = *(const float4*)(W + (size_t)(k0 + kk) * 128 + j4 * 4);
      *(float4*)(&Ws[kk][j4 * 4]) = w;
    }
    // stage A tile transposed: 32 rows x 32 k
    {
      int r = tid >> 3, k4 = tid & 7;
      int row = r0 + r;
      float4 a = make_float4(0.f, 0.f, 0.f, 0.f);
      if (row < N) a = *(const float4*)(A + (size_t)row * 128 + k0 + k4 * 4);
      As[k4 * 4 + 0][r] = a.x;
      As[k4 * 4 + 1][r] = a.y;
      As[k4 * 4 + 2][r] = a.z;
      As[k4 * 4 + 3][r] = a.w;
    }
    __syncthreads();
    #pragma unroll
    for (int k = 0; k < 32; ++k) {
      float4 a = *(const float4*)(&As[k][ty * 4]);
      float4 b = *(const float4*)(&Ws[k][tx * 4]);
      float av[4] = {a.x, a.y, a.z, a.w};
      float bv[4] = {b.x, b.y, b.z, b.w};
      #pragma unroll
      for (int i = 0; i < 4; ++i)
        #pragma unroll
        for (int j = 0; j < 4; ++j)
          acc[i][j] = fmaf(av[i], bv[j], acc[i][j]);
    }
    __syncthreads();
  }
  #pragma unroll
  for (int i = 0; i < 4; ++i) {
    int row = r0 + ty * 4 + i;
    if (row < N)
      *(float4*)(C + (size_t)row * 128 + tx * 4) =
          make_float4(acc[i][0], acc[i][1], acc[i][2], acc[i][3]);
  }
}

// ---------------- aggregation: one wave per node ----------------
__global__ __launch_bounds__(256) void k_agg(const float* __restrict__ t,
                                             const int* __restrict__ csr_src,
                                             const float* __restrict__ normv,
                                             const int* __restrict__ offs,
                                             const float* __restrict__ bias,
                                             float* __restrict__ hout, int N, int relu) {
  int node = blockIdx.x * 4 + (threadIdx.x >> 6);
  int lane = threadIdx.x & 63;
  if (node >= N) return;
  int beg = offs[node], end = offs[node + 1];
  float ax = 0.f, ay = 0.f;
  #pragma unroll 4
  for (int e = beg; e < end; ++e) {
    int s = csr_src[e];
    float w = normv[e];
    float2 v = *(const float2*)(t + (size_t)s * 128 + lane * 2);
    ax = fmaf(w, v.x, ax);
    ay = fmaf(w, v.y, ay);
  }
  float2 b = *(const float2*)(bias + lane * 2);
  ax += b.x; ay += b.y;
  if (relu) { ax = fmaxf(ax, 0.f); ay = fmaxf(ay, 0.f); }
  *(float2*)(hout + (size_t)node * 128 + lane * 2) = make_float2(ax, ay);
}

// layer-3 aggregation fused with mean-pool numerator: per node dot(h3, Wp) -> atomic per graph
__global__ __launch_bounds__(256) void k_agg_pool(const float* __restrict__ t,
                                                  const int* __restrict__ csr_src,
                                                  const float* __restrict__ normv,
                                                  const int* __restrict__ offs,
                                                  const float* __restrict__ bias,
                                                  const float* __restrict__ Wp,
                                                  const int* __restrict__ batch,
                                                  float* accB, int N) {
  int node = blockIdx.x * 4 + (threadIdx.x >> 6);
  int lane = threadIdx.x & 63;
  if (node >= N) return;
  int beg = offs[node], end = offs[node + 1];
  float ax = 0.f, ay = 0.f;
  #pragma unroll 4
  for (int e = beg; e < end; ++e) {
    int s = csr_src[e];
    float w = normv[e];
    float2 v = *(const float2*)(t + (size_t)s * 128 + lane * 2);
    ax = fmaf(w, v.x, ax);
    ay = fmaf(w, v.y, ay);
  }
  float2 b = *(const float2*)(bias + lane * 2);
  float2 wp = *(const float2*)(Wp + lane * 2);
  float p = (ax + b.x) * wp.x + (ay + b.y) * wp.y;
  #pragma unroll
  for (int s = 32; s; s >>= 1) p += __shfl_xor(p, s);
  if (lane == 0) atomicAdd(&accB[batch[node]], p);
}

__global__ __launch_bounds__(64) void k_final(const float* __restrict__ accB,
                                              const int* __restrict__ cntB,
                                              const float* __restrict__ bp,
                                              float* out, int B) {
  int b = blockIdx.x * 64 + threadIdx.x;
  if (b < B) {
    float c = (float)(cntB[b] > 1 ? cntB[b] : 1);
    out[b] = accB[b] / c + bp[0];
  }
}

// ---------------- launch ----------------

extern "C" void kernel_launch(void* const* d_in, const int* in_sizes, int n_in,
                              void* d_out, int out_size, void* d_ws, size_t ws_size,
                              hipStream_t stream) {
  const float* x    = (const float*)d_in[0];
  const int*   ei   = (const int*)d_in[1];
  const int*   batch= (const int*)d_in[2];
  const float* W1   = (const float*)d_in[3];
  const float* b1   = (const float*)d_in[4];
  const float* W2   = (const float*)d_in[5];
  const float* b2   = (const float*)d_in[6];
  const float* W3   = (const float*)d_in[7];
  const float* b3   = (const float*)d_in[8];
  const float* Wp   = (const float*)d_in[9];
  const float* bp   = (const float*)d_in[10];
  float* out = (float*)d_out;

  int N = in_sizes[0] / D;
  int E = in_sizes[1] / 2;
  int B = out_size;
  int M = E + N;

  char* p = (char*)d_ws;
  int*   cnt     = (int*)p;   p += (size_t)N * 4;
  int*   offs    = (int*)p;   p += (size_t)(N + 1) * 4;
  int*   cursor  = (int*)p;   p += (size_t)N * 4;
  int*   csr_src = (int*)p;   p += (size_t)M * 4;
  float* normv   = (float*)p; p += (size_t)M * 4;
  float* dinv    = (float*)p; p += (size_t)N * 4;
  float* tbuf    = (float*)p; p += (size_t)N * D * 4;
  float* hbuf    = (float*)p; p += (size_t)N * D * 4;
  float* accB    = (float*)p; p += (size_t)B * 4;
  int*   cntB    = (int*)p;   p += (size_t)B * 4;

  int gN  = (N + 255) / 256;
  int gEN = (E + N + 255) / 256;
  int gG  = (N + 31) / 32;
  int gA  = (N + 3) / 4;

  k_init <<<gN, 256, 0, stream>>>(cnt, N, accB, cntB, B);
  k_count<<<gEN, 256, 0, stream>>>(ei, E, batch, N, cnt, cntB);
  k_dinv <<<gN, 256, 0, stream>>>(cnt, dinv, N);
  k_scan <<<1, 1024, 0, stream>>>(cnt, offs, cursor, N);
  k_fill <<<gEN, 256, 0, stream>>>(ei, E, N, dinv, cursor, csr_src, normv);

  k_gemm<<<gG, 256, 0, stream>>>(x, W1, tbuf, N);
  k_agg <<<gA, 256, 0, stream>>>(tbuf, csr_src, normv, offs, b1, hbuf, N, 1);
  k_gemm<<<gG, 256, 0, stream>>>(hbuf, W2, tbuf, N);
  k_agg <<<gA, 256, 0, stream>>>(tbuf, csr_src, normv, offs, b2, hbuf, N, 1);
  k_gemm<<<gG, 256, 0, stream>>>(hbuf, W3, tbuf, N);
  k_agg_pool<<<gA, 256, 0, stream>>>(tbuf, csr_src, normv, offs, b3, Wp, batch, accB, N);
  k_final<<<(B + 63) / 64, 64, 0, stream>>>(accB, cntB, bp, out, B);
}